// Round 11
// baseline (3576.902 us; speedup 1.0000x reference)
//
#include <hip/hip_runtime.h>
#include <math.h>

#define B_ 64
#define T_ 32
#define S_ 64
#define E_ 512
#define H_ 1024
#define C_ 2048
#define G_ 3072
#define NBLK 256
#define FLSTR 16   // 16 uints = 64B padding per flag slot

typedef __bf16 bf16_t;
typedef bf16_t bf16x8 __attribute__((ext_vector_type(8)));
typedef float f32x4 __attribute__((ext_vector_type(4)));
typedef unsigned long long u64;

__device__ __forceinline__ float sigm_(float x) { return 1.f / (1.f + __expf(-x)); }
__device__ __forceinline__ float tanh_(float x) { return 1.f - 2.f / (__expf(2.f * x) + 1.f); }

// ---- bypass (coherence-point) store helpers; loads stay normal/cached ----
__device__ __forceinline__ unsigned short bits_(bf16_t x)
{
    union { bf16_t b; unsigned short u; } c; c.b = x; return c.u;
}
__device__ __forceinline__ void astore_pair(bf16_t* p, bf16_t lo, bf16_t hi)
{
    unsigned u = (unsigned)bits_(lo) | ((unsigned)bits_(hi) << 16);
    __hip_atomic_store((unsigned*)p, u, __ATOMIC_RELAXED, __HIP_MEMORY_SCOPE_AGENT);
}
__device__ __forceinline__ void astore_f32(float* p, float v)
{
    union { float f; unsigned u; } c; c.f = v;
    __hip_atomic_store((unsigned*)p, c.u, __ATOMIC_RELAXED, __HIP_MEMORY_SCOPE_AGENT);
}

// split 8 consecutive f32 into hi/lo bf16x8
__device__ __forceinline__ void split8(const float* __restrict__ p, bf16x8& h, bf16x8& l)
{
    float4 a = *(const float4*)p;
    float4 b = *(const float4*)(p + 4);
    float v[8] = {a.x, a.y, a.z, a.w, b.x, b.y, b.z, b.w};
    #pragma unroll
    for (int q = 0; q < 8; ++q) {
        h[q] = (bf16_t)v[q];
        l[q] = (bf16_t)(v[q] - (float)h[q]);
    }
}

// ===================== helpers =====================
__global__ __launch_bounds__(256)
void embed_kernel(const int* __restrict__ y, const float* __restrict__ emb,
                  float* __restrict__ x)
{
    int i = blockIdx.x * 256 + threadIdx.x;      // B*T*E/4
    int row = i / (E_ / 4);
    int e4  = i % (E_ / 4);
    const float4* src = (const float4*)(emb + (size_t)y[row] * E_);
    ((float4*)(x + (size_t)row * E_))[e4] = src[e4];
}

__global__ void transpose_kernel(const float* __restrict__ in, float* __restrict__ out,
                                 int R, int Ccols)
{
    __shared__ float t[32][33];
    int r0 = blockIdx.y * 32, c0 = blockIdx.x * 32;
    t[threadIdx.y][threadIdx.x] = in[(size_t)(r0 + threadIdx.y) * Ccols + c0 + threadIdx.x];
    __syncthreads();
    out[(size_t)(c0 + threadIdx.y) * R + r0 + threadIdx.x] = t[threadIdx.x][threadIdx.y];
}

__global__ __launch_bounds__(256)
void cvt_ctx(const float* __restrict__ in, bf16_t* __restrict__ out)
{
    int i = blockIdx.x * 256 + threadIdx.x;
    const float4* s4 = (const float4*)in + 2 * i;
    float4 a = s4[0], b = s4[1];
    bf16x8 o;
    o[0] = (bf16_t)a.x; o[1] = (bf16_t)a.y; o[2] = (bf16_t)a.z; o[3] = (bf16_t)a.w;
    o[4] = (bf16_t)b.x; o[5] = (bf16_t)b.y; o[6] = (bf16_t)b.z; o[7] = (bf16_t)b.w;
    ((bf16x8*)out)[i] = o;
}

// ============ split-precision GEMM: f32 A[M,K] @ f32 Wt[N,K]^T -> f32 =======
// PERM=1: write into xg2 layout [j>>2][t][b][gate*4 + (j&3)]
#define LSTR 80

template<int ACCUM, int PERM>
__global__ __launch_bounds__(256)
void sgemm(const float* __restrict__ A, const float* __restrict__ Wt,
           float* __restrict__ out, int N, int K)
{
    __shared__ char AH[128 * LSTR];
    __shared__ char AL[128 * LSTR];
    __shared__ char WH[128 * LSTR];
    __shared__ char WL[128 * LSTR];
    const int tid = threadIdx.x;
    const int lane = tid & 63, wave = tid >> 6;
    const int m0 = blockIdx.y * 128, n0 = blockIdx.x * 128;
    const int wm = (wave & 1) * 64, wn = (wave >> 1) * 64;
    const int l15 = lane & 15, l4 = lane >> 4;

    f32x4 acc[4][4] = {};

    for (int k0 = 0; k0 < K; k0 += 32) {
        #pragma unroll
        for (int p = 0; p < 2; ++p) {
            int e = tid + p * 256;
            int row = e >> 2, ch = e & 3;
            int off = row * LSTR + ch * 16;
            bf16x8 h, l;
            split8(A + (size_t)(m0 + row) * K + k0 + ch * 8, h, l);
            *(bf16x8*)(AH + off) = h; *(bf16x8*)(AL + off) = l;
            split8(Wt + (size_t)(n0 + row) * K + k0 + ch * 8, h, l);
            *(bf16x8*)(WH + off) = h; *(bf16x8*)(WL + off) = l;
        }
        __syncthreads();
        bf16x8 ah[4], al[4], wh[4], wl[4];
        #pragma unroll
        for (int i = 0; i < 4; ++i) {
            int off = (wm + i * 16 + l15) * LSTR + l4 * 16;
            ah[i] = *(const bf16x8*)(AH + off);
            al[i] = *(const bf16x8*)(AL + off);
        }
        #pragma unroll
        for (int j = 0; j < 4; ++j) {
            int off = (wn + j * 16 + l15) * LSTR + l4 * 16;
            wh[j] = *(const bf16x8*)(WH + off);
            wl[j] = *(const bf16x8*)(WL + off);
        }
        #pragma unroll
        for (int i = 0; i < 4; ++i)
            #pragma unroll
            for (int j = 0; j < 4; ++j) {
                acc[i][j] = __builtin_amdgcn_mfma_f32_16x16x32_bf16(ah[i], wh[j], acc[i][j], 0, 0, 0);
                acc[i][j] = __builtin_amdgcn_mfma_f32_16x16x32_bf16(ah[i], wl[j], acc[i][j], 0, 0, 0);
                acc[i][j] = __builtin_amdgcn_mfma_f32_16x16x32_bf16(al[i], wh[j], acc[i][j], 0, 0, 0);
            }
        __syncthreads();
    }

    #pragma unroll
    for (int i = 0; i < 4; ++i)
        #pragma unroll
        for (int j = 0; j < 4; ++j)
            #pragma unroll
            for (int r = 0; r < 4; ++r) {
                int m = m0 + wm + i * 16 + l4 * 4 + r;
                int n = n0 + wn + j * 16 + l15;
                if (PERM) {
                    int b = m >> 5, t = m & 31;
                    int gate = n >> 10, jj = n & 1023;
                    size_t dst = (((size_t)(jj >> 2) * 32 + t) * 64 + b) * 12
                                 + gate * 4 + (jj & 3);
                    out[dst] = acc[i][j][r];
                } else if (ACCUM) {
                    out[(size_t)m * N + n] += acc[i][j][r];
                } else {
                    out[(size_t)m * N + n] = acc[i][j][r];
                }
            }
}

// ===================== persistent scan kernel =====================
#define W1H_OFF 0         // W_hh1 hi : 12 rows x 2048B
#define W1L_OFF 24576     // W_hh1 lo : 12 rows
#define W3H_OFF 49152     // W_ih2 hi : 12 rows x 4096B
#define W2H_OFF 98304     // [W_hh2 gates; WqT] hi : 16 rows x 2048B
#define W2L_OFF 131072    // lo : 16 rows -> ends 163840
#define SMEM_BYTES 163840

// Fence-free barrier (flags are relaxed agent atomics; no L2 invalidation).
__device__ __forceinline__ void gbar(unsigned* flags, unsigned* done,
                                     unsigned epoch, int blk, int tid)
{
    asm volatile("s_waitcnt vmcnt(0)" ::: "memory");
    __syncthreads();
    if (blk == 0) {
        if (tid > 0 && tid < NBLK) {
            while (__hip_atomic_load(&flags[tid * FLSTR], __ATOMIC_RELAXED,
                                     __HIP_MEMORY_SCOPE_AGENT) < epoch)
                __builtin_amdgcn_s_sleep(4);
        }
        __syncthreads();
        if (tid < 8)
            __hip_atomic_store(&done[tid * FLSTR], epoch, __ATOMIC_RELAXED,
                               __HIP_MEMORY_SCOPE_AGENT);
        __syncthreads();
    } else {
        if (tid == 0) {
            __hip_atomic_store(&flags[blk * FLSTR], epoch, __ATOMIC_RELAXED,
                               __HIP_MEMORY_SCOPE_AGENT);
            while (__hip_atomic_load(&done[(blk & 7) * FLSTR], __ATOMIC_RELAXED,
                                     __HIP_MEMORY_SCOPE_AGENT) < epoch)
                __builtin_amdgcn_s_sleep(4);
        }
        __syncthreads();
    }
}

__global__ __launch_bounds__(1024, 4)
void scan_kernel(
    const float* __restrict__ Whh1, const float* __restrict__ Whh2,
    const float* __restrict__ WqT,  const float* __restrict__ Wih2,
    const float* __restrict__ xg2,
    const float* __restrict__ b_ih1, const float* __restrict__ b_hh1,
    const float* __restrict__ b_ih2, const float* __restrict__ b_hh2,
    const float* __restrict__ bq,    const float* __restrict__ v_attn,
    const int*   __restrict__ cmask,
    const float* __restrict__ hidden,
    const float* __restrict__ cacheK, const bf16_t* __restrict__ ctxb,
    float* __restrict__ qgv, float* __restrict__ hf,
    bf16_t* __restrict__ h1H, bf16_t* __restrict__ h1L,
    float* __restrict__ attnseq, float* __restrict__ outseq,
    float* __restrict__ hfinal,
    float* __restrict__ red,
    unsigned* __restrict__ flags, unsigned* __restrict__ done)
{
    extern __shared__ char sm[];
    const int tid = threadIdx.x, blk = blockIdx.x;
    const int lane = tid & 63, wave = tid >> 6;   // 16 waves
    const int l15 = lane & 15, l4 = lane >> 4;
    const int blk4 = blk * 4;
    const int ab  = blk & 63;    // attention batch
    const int aq  = blk >> 6;    // attention quarter (0..3)
    const int kg  = wave >> 2;   // K-chunk group (0..3)
    const int bg  = wave & 3;    // batch-row group (0..3)
    float* redp = red + (size_t)blk * 4096;   // block-private scratch (cached)

    // One-time cache invalidate (stale poisoned lines), then only fresh data.
    if (tid == 0) __builtin_amdgcn_fence(__ATOMIC_ACQUIRE, "agent");
    __syncthreads();

    // ---- stage weight slices into LDS as hi/lo bf16 (swizzled) ----
    for (int e = tid; e < 12 * 128; e += 1024) {           // W_hh1 (K=1024)
        int r = e >> 7, c = e & 127;
        bf16x8 h, l;
        split8(Whh1 + (size_t)((r >> 2) * 1024 + blk4 + (r & 3)) * 1024 + c * 8, h, l);
        int off = r * 2048 + ((c * 16) ^ ((r & 7) << 4));
        *(bf16x8*)(sm + W1H_OFF + off) = h;
        *(bf16x8*)(sm + W1L_OFF + off) = l;
    }
    for (int e = tid; e < 16 * 128; e += 1024) {           // [W_hh2 gates; WqT] (K=1024)
        int r = e >> 7, c = e & 127;
        const float* src = (r < 12)
            ? Whh2 + (size_t)((r >> 2) * 1024 + blk4 + (r & 3)) * 1024 + c * 8
            : WqT + (size_t)(blk4 + r - 12) * 1024 + c * 8;
        bf16x8 h, l;
        split8(src, h, l);
        int off = r * 2048 + ((c * 16) ^ ((r & 7) << 4));
        *(bf16x8*)(sm + W2H_OFF + off) = h;
        *(bf16x8*)(sm + W2L_OFF + off) = l;
    }
    for (int e = tid; e < 12 * 256; e += 1024) {           // W_ih2 hi only (K=2048)
        int r = e >> 8, c = e & 255;
        bf16x8 h, l;
        split8(Wih2 + (size_t)((r >> 2) * 1024 + blk4 + (r & 3)) * 2048 + c * 8, h, l);
        *(bf16x8*)(sm + W3H_OFF + r * 4096 + ((c * 16) ^ ((r & 7) << 4))) = h;
    }

    // hf init (thread-private recurrent f32 state; waves 0-3 own it)
    const int j = blk4 + l15;
    if (wave < 4 && l15 < 4) {
        #pragma unroll
        for (int r2 = 0; r2 < 4; ++r2) {
            int b = wave * 16 + l4 * 4 + r2;
            hf[b * 1024 + j] = hidden[b * 1024 + j];
        }
    }

    // attention constants / pinned ctx registers (time-invariant)
    float vreg[16];
    #pragma unroll
    for (int i = 0; i < 16; ++i) vreg[i] = v_attn[lane + 64 * i];
    // ctx column cmy = aq*512 + tid/2; thread covers s = sbase..sbase+31
    const int cmy = aq * 512 + (tid >> 1);
    const int sbase = (tid & 1) * 32;
    unsigned cr[16];
    {
        const bf16_t* cb = ctxb + ((size_t)ab * 64 + sbase) * 2048 + cmy;
        #pragma unroll
        for (int q = 0; q < 16; ++q) {
            unsigned lo = bits_(cb[(size_t)(2 * q) * 2048]);
            unsigned hi = bits_(cb[(size_t)(2 * q + 1) * 2048]);
            cr[q] = lo | (hi << 16);
        }
    }

    // per-thread GRU biases (waves 0-3, l15<4) and bq (waves 0-3, l15>=12)
    float bi1r = 0, bi1z = 0, bi1n = 0, bh1r = 0, bh1z = 0, bh1n = 0;
    float bi2r = 0, bi2z = 0, bi2n = 0, bh2r = 0, bh2z = 0, bh2n = 0;
    float bqv = 0.f;
    if (wave < 4 && l15 < 4) {
        bi1r = b_ih1[j]; bi1z = b_ih1[1024 + j]; bi1n = b_ih1[2048 + j];
        bh1r = b_hh1[j]; bh1z = b_hh1[1024 + j]; bh1n = b_hh1[2048 + j];
        bi2r = b_ih2[j]; bi2z = b_ih2[1024 + j]; bi2n = b_ih2[2048 + j];
        bh2r = b_hh2[j]; bh2z = b_hh2[1024 + j]; bh2n = b_hh2[2048 + j];
    }
    if (wave < 4 && l15 >= 12) bqv = bq[blk4 + l15 - 12];

    unsigned epoch = 0;
    gbar(flags, done, ++epoch, blk, tid);

    float h1r_[4] = {0.f, 0.f, 0.f, 0.f};
    f32x4 acc1 = {0.f, 0.f, 0.f, 0.f};

    for (int t = 0; t < T_; ++t) {
        // ===== P0: gh1 = h @ W_hh1^T (3-term, 4-way K-split) + GRU1 =====
        {
            f32x4 a0 = {0.f, 0.f, 0.f, 0.f};
            const int brow = bg * 16 + l15;
            const float* asrc = (t == 0) ? hidden + (size_t)brow * 1024
                                         : outseq + ((size_t)brow * T_ + t - 1) * 1024;
            #pragma unroll
            for (int kq = 0; kq < 8; ++kq) {
                int kk = kg * 8 + kq;
                bf16x8 avh, avl;
                split8(asrc + kk * 32 + l4 * 8, avh, avl);
                int boff = (kk * 64 + l4 * 16) ^ ((l15 & 7) << 4);
                bf16x8 bvh = *(const bf16x8*)(sm + W1H_OFF + l15 * 2048 + boff);
                bf16x8 bvl = *(const bf16x8*)(sm + W1L_OFF + l15 * 2048 + boff);
                a0 = __builtin_amdgcn_mfma_f32_16x16x32_bf16(avh, bvh, a0, 0, 0, 0);
                a0 = __builtin_amdgcn_mfma_f32_16x16x32_bf16(avl, bvh, a0, 0, 0, 0);
                a0 = __builtin_amdgcn_mfma_f32_16x16x32_bf16(avh, bvl, a0, 0, 0, 0);
            }
            if (kg) *(f32x4*)(redp + (size_t)wave * 256 + lane * 4) = a0;
            __syncthreads();
            if (wave < 4) {
                #pragma unroll
                for (int g = 1; g < 4; ++g) {
                    f32x4 p = *(const f32x4*)(redp + (size_t)(g * 4 + wave) * 256 + lane * 4);
                    a0[0] += p[0]; a0[1] += p[1]; a0[2] += p[2]; a0[3] += p[3];
                }
                const float* xg = xg2 + (((size_t)blk * 32 + t) * 64) * 12;
                #pragma unroll
                for (int r2 = 0; r2 < 4; ++r2) {
                    float gr = a0[r2];
                    float gz = __shfl(a0[r2], (lane & 48) | (l15 + 4), 64);
                    float gn = __shfl(a0[r2], (lane & 48) | (l15 + 8), 64);
                    float h1v = 0.f;
                    int b = wave * 16 + l4 * 4 + r2;
                    if (l15 < 4) {
                        float rr = sigm_(xg[b * 12 + l15]     + bi1r + gr + bh1r);
                        float zz = sigm_(xg[b * 12 + 4 + l15] + bi1z + gz + bh1z);
                        float nn = tanh_(xg[b * 12 + 8 + l15] + bi1n + rr * (gn + bh1n));
                        h1v = (1.f - zz) * nn + zz * hf[b * 1024 + j];
                        h1r_[r2] = h1v;
                    }
                    float h1o = __shfl(h1v, lane + 1, 64);
                    if (l15 < 4 && (l15 & 1) == 0) {
                        bf16_t hS = (bf16_t)h1v, hO = (bf16_t)h1o;
                        size_t vo = ((size_t)t * 64 + b) * 1024 + j;
                        astore_pair(h1H + vo, hS, hO);
                        astore_pair(h1L + vo,
                                    (bf16_t)(h1v - (float)hS), (bf16_t)(h1o - (float)hO));
                    }
                }
            }
        }
        gbar(flags, done, ++epoch, blk, tid);

        // ===== P1: [gh2 | q] = h1 @ [W_hh2 ; WqT]^T (3-term, K-split) =====
        {
            f32x4 a1 = {0.f, 0.f, 0.f, 0.f};
            const int brow = bg * 16 + l15;
            const bf16_t* ah = h1H + ((size_t)t * 64 + brow) * 1024;
            const bf16_t* al = h1L + ((size_t)t * 64 + brow) * 1024;
            #pragma unroll
            for (int kq = 0; kq < 8; ++kq) {
                int kk = kg * 8 + kq;
                bf16x8 avh = *(const bf16x8*)(ah + kk * 32 + l4 * 8);
                bf16x8 avl = *(const bf16x8*)(al + kk * 32 + l4 * 8);
                int boff = (kk * 64 + l4 * 16) ^ ((l15 & 7) << 4);
                bf16x8 bvh = *(const bf16x8*)(sm + W2H_OFF + l15 * 2048 + boff);
                bf16x8 bvl = *(const bf16x8*)(sm + W2L_OFF + l15 * 2048 + boff);
                a1 = __builtin_amdgcn_mfma_f32_16x16x32_bf16(avh, bvh, a1, 0, 0, 0);
                a1 = __builtin_amdgcn_mfma_f32_16x16x32_bf16(avl, bvh, a1, 0, 0, 0);
                a1 = __builtin_amdgcn_mfma_f32_16x16x32_bf16(avh, bvl, a1, 0, 0, 0);
            }
            if (kg) *(f32x4*)(redp + (size_t)wave * 256 + lane * 4) = a1;
            __syncthreads();
            if (wave < 4) {
                acc1 = a1;
                #pragma unroll
                for (int g = 1; g < 4; ++g) {
                    f32x4 p = *(const f32x4*)(redp + (size_t)(g * 4 + wave) * 256 + lane * 4);
                    acc1[0] += p[0]; acc1[1] += p[1]; acc1[2] += p[2]; acc1[3] += p[3];
                }
                if (l15 >= 12) {
                    int jq = blk4 + l15 - 12;
                    #pragma unroll
                    for (int r2 = 0; r2 < 4; ++r2)
                        astore_f32(&qgv[((size_t)t * 64 + (wave * 16 + l4 * 4 + r2)) * 1024 + jq],
                                   acc1[r2] + bqv);
                }
            }
        }
        gbar(flags, done, ++epoch, blk, tid);

        // ===== P2 (merged): scores (all 64, L2 cacheK) + softmax + PV =====
        {
            const float* qrow = qgv + ((size_t)t * 64 + ab) * 1024;   // q + bq
            float qreg[16];
            #pragma unroll
            for (int i = 0; i < 16; ++i) qreg[i] = qrow[lane + 64 * i];
            #pragma unroll
            for (int sl = 0; sl < 4; ++sl) {
                int s = wave * 4 + sl;
                const float* ck = cacheK + ((size_t)ab * 64 + s) * 1024;
                float sum = 0.f;
                #pragma unroll
                for (int i = 0; i < 16; ++i)
                    sum += tanh_(qreg[i] + ck[lane + 64 * i]) * vreg[i];
                #pragma unroll
                for (int off = 32; off; off >>= 1) sum += __shfl_down(sum, off, 64);
                if (lane == 0) redp[s] = sum;
            }
            __syncthreads();
            float v = (cmask[ab * 64 + lane] != 0) ? -3.4e38f : redp[lane];
            float mx = v;
            #pragma unroll
            for (int off = 32; off; off >>= 1) mx = fmaxf(mx, __shfl_xor(mx, off, 64));
            float e = __expf(v - mx);
            float sden = e;
            #pragma unroll
            for (int off = 32; off; off >>= 1) sden += __shfl_xor(sden, off, 64);
            float prv = e / sden;

            float sum = 0.f;
            #pragma unroll
            for (int q = 0; q < 16; ++q) {
                float p0 = __shfl(prv, sbase + 2 * q, 64);
                float p1 = __shfl(prv, sbase + 2 * q + 1, 64);
                sum += p0 * __uint_as_float(cr[q] << 16);
                sum += p1 * __uint_as_float(cr[q] & 0xffff0000u);
            }
            sum += __shfl_xor(sum, 1, 64);
            if ((tid & 1) == 0)
                astore_f32(attnseq + ((size_t)ab * T_ + t) * 2048 + cmy, sum);
        }
        gbar(flags, done, ++epoch, blk, tid);

        // ===== P3: gi2 = attn @ W_ih2^T (A split, W hi; K-split) + GRU2 =====
        {
            f32x4 a3 = {0.f, 0.f, 0.f, 0.f};
            const int brow = bg * 16 + l15;
            const float* aptr = attnseq + ((size_t)brow * T_ + t) * 2048;
            #pragma unroll
            for (int kq = 0; kq < 16; ++kq) {
                int kk = kg * 16 + kq;
                bf16x8 avh, avl;
                split8(aptr + kk * 32 + l4 * 8, avh, avl);
                bf16x8 bvh = *(const bf16x8*)(sm + W3H_OFF + l15 * 4096 +
                                              ((kk * 64 + l4 * 16) ^ ((l15 & 7) << 4)));
                a3 = __builtin_amdgcn_mfma_f32_16x16x32_bf16(avh, bvh, a3, 0, 0, 0);
                a3 = __builtin_amdgcn_mfma_f32_16x16x32_bf16(avl, bvh, a3, 0, 0, 0);
            }
            if (kg) *(f32x4*)(redp + (size_t)wave * 256 + lane * 4) = a3;
            __syncthreads();
            if (wave < 4) {
                #pragma unroll
                for (int g = 1; g < 4; ++g) {
                    f32x4 p = *(const f32x4*)(redp + (size_t)(g * 4 + wave) * 256 + lane * 4);
                    a3[0] += p[0]; a3[1] += p[1]; a3[2] += p[2]; a3[3] += p[3];
                }
                #pragma unroll
                for (int r2 = 0; r2 < 4; ++r2) {
                    float ir  = a3[r2];
                    float iz  = __shfl(a3[r2], (lane & 48) | (l15 + 4), 64);
                    float in2 = __shfl(a3[r2], (lane & 48) | (l15 + 8), 64);
                    float hr  = acc1[r2];
                    float hz  = __shfl(acc1[r2], (lane & 48) | (l15 + 4), 64);
                    float hn  = __shfl(acc1[r2], (lane & 48) | (l15 + 8), 64);
                    int b = wave * 16 + l4 * 4 + r2;
                    if (l15 < 4) {
                        float rr = sigm_(ir + bi2r + hr + bh2r);
                        float zz = sigm_(iz + bi2z + hz + bh2z);
                        float nn = tanh_(in2 + bi2n + rr * (hn + bh2n));
                        float h2 = (1.f - zz) * nn + zz * h1r_[r2];
                        hf[b * 1024 + j] = h2;
                        astore_f32(&outseq[((size_t)b * T_ + t) * 1024 + j], h2);
                        if (t == T_ - 1) hfinal[b * 1024 + j] = h2;
                    }
                }
            }
        }
        gbar(flags, done, ++epoch, blk, tid);
    }
}

// ===================== final logits =====================
__global__ __launch_bounds__(256)
void final_kernel(const float* __restrict__ Lacc,
                  const float* __restrict__ bi, const float* __restrict__ bh,
                  const float* __restrict__ bc, float* __restrict__ out)
{
    int i = blockIdx.x * 256 + threadIdx.x;
    int e = i & 511;
    out[i] = tanh_(Lacc[i] + bi[e] + bh[e] + bc[e]);
}

// ===================== host =====================
extern "C" void kernel_launch(void* const* d_in, const int* in_sizes, int n_in,
                              void* d_out, int out_size, void* d_ws, size_t ws_size,
                              hipStream_t stream)
{
    const int*   y       = (const int*)  d_in[0];
    const float* context = (const float*)d_in[1];
    const int*   cmask   = (const int*)  d_in[2];
    const float* hidden  = (const float*)d_in[3];
    const float* emb     = (const float*)d_in[4];
    const float* W_ih1   = (const float*)d_in[5];
    const float* W_hh1   = (const float*)d_in[6];
    const float* b_ih1   = (const float*)d_in[7];
    const float* b_hh1   = (const float*)d_in[8];
    const float* Wq      = (const float*)d_in[9];
    const float* bq      = (const float*)d_in[10];
    const float* Wk      = (const float*)d_in[11];
    const float* v_attn  = (const float*)d_in[12];
    const float* W_ih2   = (const float*)d_in[13];
    const float* W_hh2   = (const float*)d_in[14];
    const float* b_ih2   = (const float*)d_in[15];
    const float* b_hh2   = (const float*)d_in[16];
    const float* Wi      = (const float*)d_in[17];
    const float* bi      = (const float*)d_in[18];
    const float* Wh      = (const float*)d_in[19];
    const float* bh      = (const float*)d_in[20];
    const float* Wc      = (const float*)d_in[21];
    const float* bc      = (const float*)d_in[22];

    char* ws = (char*)d_ws;
    size_t o = 0;
    auto alloc = [&](size_t bytes) { char* p = ws + o; o += (bytes + 255) & ~(size_t)255; return p; };
    unsigned* flags = (unsigned*)alloc(NBLK * FLSTR * 4);
    unsigned* done  = (unsigned*)alloc(8 * FLSTR * 4);
    float*  x       = (float*) alloc((size_t)2048 * 512 * 4);
    float*  WkT     = (float*) alloc((size_t)1024 * 2048 * 4);
    float*  WqT     = (float*) alloc((size_t)1024 * 1024 * 4);
    bf16_t* ctxb    = (bf16_t*)alloc((size_t)4096 * 2048 * 2);
    float*  xg2     = (float*) alloc((size_t)2048 * 3072 * 4);      // permuted Xg
    float*  Lacc    = (float*) alloc((size_t)2048 * 512 * 4);
    float*  cacheK  = (float*) alloc((size_t)4096 * 1024 * 4);
    float*  qgv     = (float*) alloc((size_t)T_ * 64 * 1024 * 4);
    float*  hf      = (float*) alloc((size_t)64 * 1024 * 4);
    bf16_t* h1H     = (bf16_t*)alloc((size_t)T_ * 64 * 1024 * 2);
    bf16_t* h1L     = (bf16_t*)alloc((size_t)T_ * 64 * 1024 * 2);
    float*  attnseq = (float*) alloc((size_t)2048 * 2048 * 4);
    float*  outseq  = (float*) alloc((size_t)2048 * 1024 * 4);
    float*  red     = (float*) alloc((size_t)NBLK * 4096 * 4);      // block-private scratch

    hipMemsetAsync(flags, 0, (NBLK * FLSTR + 8 * FLSTR) * 4, stream);

    embed_kernel<<<(B_*T_*E_/4 + 255)/256, 256, 0, stream>>>(y, emb, x);
    transpose_kernel<<<dim3(1024/32, 2048/32), dim3(32,32), 0, stream>>>(Wk, WkT, 2048, 1024);
    transpose_kernel<<<dim3(1024/32, 1024/32), dim3(32,32), 0, stream>>>(Wq, WqT, 1024, 1024);
    cvt_ctx<<<(4096*2048/8)/256, 256, 0, stream>>>(context, ctxb);

    sgemm<0, 1><<<dim3(G_/128, 16), 256, 0, stream>>>(x, W_ih1, xg2, G_, E_);   // Xg permuted
    sgemm<0, 0><<<dim3(E_/128, 16), 256, 0, stream>>>(x, Wi, Lacc, E_, E_);
    sgemm<0, 0><<<dim3(H_/128, 32), 256, 0, stream>>>(context, WkT, cacheK, H_, C_);

    hipFuncSetAttribute((const void*)scan_kernel, hipFuncAttributeMaxDynamicSharedMemorySize, SMEM_BYTES);
    scan_kernel<<<NBLK, 1024, SMEM_BYTES, stream>>>(
        W_hh1, W_hh2, WqT, W_ih2, xg2,
        b_ih1, b_hh1, b_ih2, b_hh2, bq, v_attn, cmask, hidden, cacheK, ctxb,
        qgv, hf, h1H, h1L, attnseq, outseq,
        (float*)d_out + (size_t)B_ * T_ * E_, red, flags, done);

    sgemm<1, 0><<<dim3(E_/128, 16), 256, 0, stream>>>(outseq, Wh, Lacc, E_, H_);
    sgemm<1, 0><<<dim3(E_/128, 16), 256, 0, stream>>>(attnseq, Wc, Lacc, E_, C_);

    final_kernel<<<(B_*T_*E_)/256, 256, 0, stream>>>(Lacc, bi, bh, bc, (float*)d_out);
}

// Round 12
// 3546.419 us; speedup vs baseline: 1.0086x; 1.0086x over previous
//
#include <hip/hip_runtime.h>
#include <math.h>

#define B_ 64
#define T_ 32
#define S_ 64
#define E_ 512
#define H_ 1024
#define C_ 2048
#define G_ 3072
#define NBLK 256
#define FLSTR 16   // 16 uints = 64B padding per flag slot

typedef __bf16 bf16_t;
typedef bf16_t bf16x8 __attribute__((ext_vector_type(8)));
typedef float f32x4 __attribute__((ext_vector_type(4)));
typedef unsigned long long u64;

__device__ __forceinline__ float sigm_(float x) { return 1.f / (1.f + __expf(-x)); }
__device__ __forceinline__ float tanh_(float x) { return 1.f - 2.f / (__expf(2.f * x) + 1.f); }

// ---- bypass (coherence-point) store helpers; loads stay normal/cached ----
__device__ __forceinline__ unsigned short bits_(bf16_t x)
{
    union { bf16_t b; unsigned short u; } c; c.b = x; return c.u;
}
__device__ __forceinline__ void astore_pair(bf16_t* p, bf16_t lo, bf16_t hi)
{
    unsigned u = (unsigned)bits_(lo) | ((unsigned)bits_(hi) << 16);
    __hip_atomic_store((unsigned*)p, u, __ATOMIC_RELAXED, __HIP_MEMORY_SCOPE_AGENT);
}
__device__ __forceinline__ void astore_f32(float* p, float v)
{
    union { float f; unsigned u; } c; c.f = v;
    __hip_atomic_store((unsigned*)p, c.u, __ATOMIC_RELAXED, __HIP_MEMORY_SCOPE_AGENT);
}

// split 8 consecutive f32 into hi/lo bf16x8
__device__ __forceinline__ void split8(const float* __restrict__ p, bf16x8& h, bf16x8& l)
{
    float4 a = *(const float4*)p;
    float4 b = *(const float4*)(p + 4);
    float v[8] = {a.x, a.y, a.z, a.w, b.x, b.y, b.z, b.w};
    #pragma unroll
    for (int q = 0; q < 8; ++q) {
        h[q] = (bf16_t)v[q];
        l[q] = (bf16_t)(v[q] - (float)h[q]);
    }
}

// ===================== helpers =====================
__global__ __launch_bounds__(256)
void embed_kernel(const int* __restrict__ y, const float* __restrict__ emb,
                  float* __restrict__ x)
{
    int i = blockIdx.x * 256 + threadIdx.x;      // B*T*E/4
    int row = i / (E_ / 4);
    int e4  = i % (E_ / 4);
    const float4* src = (const float4*)(emb + (size_t)y[row] * E_);
    ((float4*)(x + (size_t)row * E_))[e4] = src[e4];
}

__global__ void transpose_kernel(const float* __restrict__ in, float* __restrict__ out,
                                 int R, int Ccols)
{
    __shared__ float t[32][33];
    int r0 = blockIdx.y * 32, c0 = blockIdx.x * 32;
    t[threadIdx.y][threadIdx.x] = in[(size_t)(r0 + threadIdx.y) * Ccols + c0 + threadIdx.x];
    __syncthreads();
    out[(size_t)(c0 + threadIdx.y) * R + r0 + threadIdx.x] = t[threadIdx.x][threadIdx.y];
}

__global__ __launch_bounds__(256)
void cvt_ctx(const float* __restrict__ in, bf16_t* __restrict__ out)
{
    int i = blockIdx.x * 256 + threadIdx.x;
    const float4* s4 = (const float4*)in + 2 * i;
    float4 a = s4[0], b = s4[1];
    bf16x8 o;
    o[0] = (bf16_t)a.x; o[1] = (bf16_t)a.y; o[2] = (bf16_t)a.z; o[3] = (bf16_t)a.w;
    o[4] = (bf16_t)b.x; o[5] = (bf16_t)b.y; o[6] = (bf16_t)b.z; o[7] = (bf16_t)b.w;
    ((bf16x8*)out)[i] = o;
}

// ============ split-precision GEMM: f32 A[M,K] @ f32 Wt[N,K]^T -> f32 =======
// PERM=1: write into xg2 layout [j>>2][t][b][gate*4 + (j&3)]
#define LSTR 80

template<int ACCUM, int PERM>
__global__ __launch_bounds__(256)
void sgemm(const float* __restrict__ A, const float* __restrict__ Wt,
           float* __restrict__ out, int N, int K)
{
    __shared__ char AH[128 * LSTR];
    __shared__ char AL[128 * LSTR];
    __shared__ char WH[128 * LSTR];
    __shared__ char WL[128 * LSTR];
    const int tid = threadIdx.x;
    const int lane = tid & 63, wave = tid >> 6;
    const int m0 = blockIdx.y * 128, n0 = blockIdx.x * 128;
    const int wm = (wave & 1) * 64, wn = (wave >> 1) * 64;
    const int l15 = lane & 15, l4 = lane >> 4;

    f32x4 acc[4][4] = {};

    for (int k0 = 0; k0 < K; k0 += 32) {
        #pragma unroll
        for (int p = 0; p < 2; ++p) {
            int e = tid + p * 256;
            int row = e >> 2, ch = e & 3;
            int off = row * LSTR + ch * 16;
            bf16x8 h, l;
            split8(A + (size_t)(m0 + row) * K + k0 + ch * 8, h, l);
            *(bf16x8*)(AH + off) = h; *(bf16x8*)(AL + off) = l;
            split8(Wt + (size_t)(n0 + row) * K + k0 + ch * 8, h, l);
            *(bf16x8*)(WH + off) = h; *(bf16x8*)(WL + off) = l;
        }
        __syncthreads();
        bf16x8 ah[4], al[4], wh[4], wl[4];
        #pragma unroll
        for (int i = 0; i < 4; ++i) {
            int off = (wm + i * 16 + l15) * LSTR + l4 * 16;
            ah[i] = *(const bf16x8*)(AH + off);
            al[i] = *(const bf16x8*)(AL + off);
        }
        #pragma unroll
        for (int j = 0; j < 4; ++j) {
            int off = (wn + j * 16 + l15) * LSTR + l4 * 16;
            wh[j] = *(const bf16x8*)(WH + off);
            wl[j] = *(const bf16x8*)(WL + off);
        }
        #pragma unroll
        for (int i = 0; i < 4; ++i)
            #pragma unroll
            for (int j = 0; j < 4; ++j) {
                acc[i][j] = __builtin_amdgcn_mfma_f32_16x16x32_bf16(ah[i], wh[j], acc[i][j], 0, 0, 0);
                acc[i][j] = __builtin_amdgcn_mfma_f32_16x16x32_bf16(ah[i], wl[j], acc[i][j], 0, 0, 0);
                acc[i][j] = __builtin_amdgcn_mfma_f32_16x16x32_bf16(al[i], wh[j], acc[i][j], 0, 0, 0);
            }
        __syncthreads();
    }

    #pragma unroll
    for (int i = 0; i < 4; ++i)
        #pragma unroll
        for (int j = 0; j < 4; ++j)
            #pragma unroll
            for (int r = 0; r < 4; ++r) {
                int m = m0 + wm + i * 16 + l4 * 4 + r;
                int n = n0 + wn + j * 16 + l15;
                if (PERM) {
                    int b = m >> 5, t = m & 31;
                    int gate = n >> 10, jj = n & 1023;
                    size_t dst = (((size_t)(jj >> 2) * 32 + t) * 64 + b) * 12
                                 + gate * 4 + (jj & 3);
                    out[dst] = acc[i][j][r];
                } else if (ACCUM) {
                    out[(size_t)m * N + n] += acc[i][j][r];
                } else {
                    out[(size_t)m * N + n] = acc[i][j][r];
                }
            }
}

// ===================== persistent scan kernel =====================
#define W1H_OFF 0         // W_hh1 hi : 12 rows x 2048B
#define W1L_OFF 24576     // W_hh1 lo : 12 rows
#define W3H_OFF 49152     // W_ih2 hi : 12 rows x 4096B
#define W2H_OFF 98304     // [W_hh2 gates; WqT] hi : 16 rows x 2048B
#define W2L_OFF 131072    // lo : 16 rows -> ends 163840
#define SMEM_BYTES 163840

// Fence-free barrier (flags are relaxed agent atomics; no L2 invalidation).
__device__ __forceinline__ void gbar(unsigned* flags, unsigned* done,
                                     unsigned epoch, int blk, int tid)
{
    asm volatile("s_waitcnt vmcnt(0)" ::: "memory");
    __syncthreads();
    if (blk == 0) {
        if (tid > 0 && tid < NBLK) {
            while (__hip_atomic_load(&flags[tid * FLSTR], __ATOMIC_RELAXED,
                                     __HIP_MEMORY_SCOPE_AGENT) < epoch)
                __builtin_amdgcn_s_sleep(4);
        }
        __syncthreads();
        if (tid < 8)
            __hip_atomic_store(&done[tid * FLSTR], epoch, __ATOMIC_RELAXED,
                               __HIP_MEMORY_SCOPE_AGENT);
        __syncthreads();
    } else {
        if (tid == 0) {
            __hip_atomic_store(&flags[blk * FLSTR], epoch, __ATOMIC_RELAXED,
                               __HIP_MEMORY_SCOPE_AGENT);
            while (__hip_atomic_load(&done[(blk & 7) * FLSTR], __ATOMIC_RELAXED,
                                     __HIP_MEMORY_SCOPE_AGENT) < epoch)
                __builtin_amdgcn_s_sleep(4);
        }
        __syncthreads();
    }
}

__global__ __launch_bounds__(1024, 4)
void scan_kernel(
    const float* __restrict__ Whh1, const float* __restrict__ Whh2,
    const float* __restrict__ WqT,  const float* __restrict__ Wih2,
    const float* __restrict__ xg2,
    const float* __restrict__ b_ih1, const float* __restrict__ b_hh1,
    const float* __restrict__ b_ih2, const float* __restrict__ b_hh2,
    const float* __restrict__ bq,    const float* __restrict__ v_attn,
    const int*   __restrict__ cmask,
    const float* __restrict__ hidden,
    const float* __restrict__ cacheK, const bf16_t* __restrict__ ctxb,
    float* __restrict__ qgv, float* __restrict__ hf,
    bf16_t* __restrict__ h1H, bf16_t* __restrict__ h1L,
    float* __restrict__ attnseq, float* __restrict__ outseq,
    float* __restrict__ hfinal,
    float* __restrict__ red,
    unsigned* __restrict__ flags, unsigned* __restrict__ done)
{
    extern __shared__ char sm[];
    const int tid = threadIdx.x, blk = blockIdx.x;
    const int lane = tid & 63, wave = tid >> 6;   // 16 waves
    const int l15 = lane & 15, l4 = lane >> 4;
    const int blk4 = blk * 4;
    const int ab  = blk & 63;    // attention batch
    const int aq  = blk >> 6;    // attention quarter (0..3)
    float* redp = red + (size_t)blk * 1024;   // block-private scratch (cached)

    // One-time cache invalidate (stale poisoned lines), then only fresh data.
    if (tid == 0) __builtin_amdgcn_fence(__ATOMIC_ACQUIRE, "agent");
    __syncthreads();

    // ---- stage weight slices into LDS as hi/lo bf16 (swizzled) ----
    for (int e = tid; e < 12 * 128; e += 1024) {           // W_hh1 (K=1024)
        int r = e >> 7, c = e & 127;
        bf16x8 h, l;
        split8(Whh1 + (size_t)((r >> 2) * 1024 + blk4 + (r & 3)) * 1024 + c * 8, h, l);
        int off = r * 2048 + ((c * 16) ^ ((r & 7) << 4));
        *(bf16x8*)(sm + W1H_OFF + off) = h;
        *(bf16x8*)(sm + W1L_OFF + off) = l;
    }
    for (int e = tid; e < 16 * 128; e += 1024) {           // [W_hh2 gates; WqT] (K=1024)
        int r = e >> 7, c = e & 127;
        const float* src = (r < 12)
            ? Whh2 + (size_t)((r >> 2) * 1024 + blk4 + (r & 3)) * 1024 + c * 8
            : WqT + (size_t)(blk4 + r - 12) * 1024 + c * 8;
        bf16x8 h, l;
        split8(src, h, l);
        int off = r * 2048 + ((c * 16) ^ ((r & 7) << 4));
        *(bf16x8*)(sm + W2H_OFF + off) = h;
        *(bf16x8*)(sm + W2L_OFF + off) = l;
    }
    for (int e = tid; e < 12 * 256; e += 1024) {           // W_ih2 hi only (K=2048)
        int r = e >> 8, c = e & 255;
        bf16x8 h, l;
        split8(Wih2 + (size_t)((r >> 2) * 1024 + blk4 + (r & 3)) * 2048 + c * 8, h, l);
        *(bf16x8*)(sm + W3H_OFF + r * 4096 + ((c * 16) ^ ((r & 7) << 4))) = h;
    }

    // hf init (thread-private recurrent f32 state)
    const int j = blk4 + l15;
    if (wave < 4 && l15 < 4) {
        #pragma unroll
        for (int r2 = 0; r2 < 4; ++r2) {
            int b = wave * 16 + l4 * 4 + r2;
            hf[b * 1024 + j] = hidden[b * 1024 + j];
        }
    }

    // ---- attention data pinned in REGISTERS (time-invariant) ----
    float vreg[16];
    #pragma unroll
    for (int i = 0; i < 16; ++i) vreg[i] = v_attn[lane + 64 * i];
    // cacheK: 4 rows per wave (s = wave*4 + sl), lane holds ck[lane + 64*i]
    float ckreg[4][16];
    #pragma unroll
    for (int sl = 0; sl < 4; ++sl) {
        const float* ck = cacheK + ((size_t)ab * 64 + wave * 4 + sl) * 1024;
        #pragma unroll
        for (int i = 0; i < 16; ++i) ckreg[sl][i] = ck[lane + 64 * i];
    }
    // ctx column cmy = aq*512 + tid/2; this thread covers s = sbase..sbase+31
    const int cmy = aq * 512 + (tid >> 1);
    const int sbase = (tid & 1) * 32;
    unsigned cr[16];
    {
        const bf16_t* cb = ctxb + ((size_t)ab * 64 + sbase) * 2048 + cmy;
        #pragma unroll
        for (int q = 0; q < 16; ++q) {
            unsigned lo = bits_(cb[(size_t)(2 * q) * 2048]);
            unsigned hi = bits_(cb[(size_t)(2 * q + 1) * 2048]);
            cr[q] = lo | (hi << 16);
        }
    }

    // per-thread GRU biases (waves 0-3, l15<4) and bq (waves 0-3, l15>=12)
    float bi1r = 0, bi1z = 0, bi1n = 0, bh1r = 0, bh1z = 0, bh1n = 0;
    float bi2r = 0, bi2z = 0, bi2n = 0, bh2r = 0, bh2z = 0, bh2n = 0;
    float bqv = 0.f;
    if (wave < 4 && l15 < 4) {
        bi1r = b_ih1[j]; bi1z = b_ih1[1024 + j]; bi1n = b_ih1[2048 + j];
        bh1r = b_hh1[j]; bh1z = b_hh1[1024 + j]; bh1n = b_hh1[2048 + j];
        bi2r = b_ih2[j]; bi2z = b_ih2[1024 + j]; bi2n = b_ih2[2048 + j];
        bh2r = b_hh2[j]; bh2z = b_hh2[1024 + j]; bh2n = b_hh2[2048 + j];
    }
    if (wave < 4 && l15 >= 12) bqv = bq[blk4 + l15 - 12];

    unsigned epoch = 0;
    gbar(flags, done, ++epoch, blk, tid);

    float h1r_[4] = {0.f, 0.f, 0.f, 0.f};
    f32x4 acc1 = {0.f, 0.f, 0.f, 0.f};

    for (int t = 0; t < T_; ++t) {
        // ===== P0: gh1 = h @ W_hh1^T (split 3-term) + in-register GRU1 =====
        if (wave < 4) {
            f32x4 acc0 = {0.f, 0.f, 0.f, 0.f};
            const int brow = wave * 16 + l15;
            const float* asrc = (t == 0) ? hidden + (size_t)brow * 1024
                                         : outseq + ((size_t)brow * T_ + t - 1) * 1024;
            #pragma unroll 8
            for (int kk = 0; kk < 32; ++kk) {
                bf16x8 avh, avl;
                split8(asrc + kk * 32 + l4 * 8, avh, avl);
                int boff = (kk * 64 + l4 * 16) ^ ((l15 & 7) << 4);
                bf16x8 bvh = *(const bf16x8*)(sm + W1H_OFF + l15 * 2048 + boff);
                bf16x8 bvl = *(const bf16x8*)(sm + W1L_OFF + l15 * 2048 + boff);
                acc0 = __builtin_amdgcn_mfma_f32_16x16x32_bf16(avh, bvh, acc0, 0, 0, 0);
                acc0 = __builtin_amdgcn_mfma_f32_16x16x32_bf16(avl, bvh, acc0, 0, 0, 0);
                acc0 = __builtin_amdgcn_mfma_f32_16x16x32_bf16(avh, bvl, acc0, 0, 0, 0);
            }
            const float* xg = xg2 + (((size_t)blk * 32 + t) * 64) * 12;
            #pragma unroll
            for (int r2 = 0; r2 < 4; ++r2) {
                float gr = acc0[r2];
                float gz = __shfl(acc0[r2], (lane & 48) | (l15 + 4), 64);
                float gn = __shfl(acc0[r2], (lane & 48) | (l15 + 8), 64);
                float h1v = 0.f;
                int b = wave * 16 + l4 * 4 + r2;
                if (l15 < 4) {
                    float rr = sigm_(xg[b * 12 + l15]     + bi1r + gr + bh1r);
                    float zz = sigm_(xg[b * 12 + 4 + l15] + bi1z + gz + bh1z);
                    float nn = tanh_(xg[b * 12 + 8 + l15] + bi1n + rr * (gn + bh1n));
                    h1v = (1.f - zz) * nn + zz * hf[b * 1024 + j];
                    h1r_[r2] = h1v;
                }
                float h1o = __shfl(h1v, lane + 1, 64);
                if (l15 < 4 && (l15 & 1) == 0) {
                    bf16_t hS = (bf16_t)h1v, hO = (bf16_t)h1o;
                    size_t vo = ((size_t)t * 64 + b) * 1024 + j;
                    astore_pair(h1H + vo, hS, hO);
                    astore_pair(h1L + vo,
                                (bf16_t)(h1v - (float)hS), (bf16_t)(h1o - (float)hO));
                }
            }
        }
        gbar(flags, done, ++epoch, blk, tid);

        // ===== P1: [gh2 | q] = h1 @ [W_hh2 ; WqT]^T (split 3-term) =====
        if (wave < 4) {
            acc1 = (f32x4){0.f, 0.f, 0.f, 0.f};
            const int brow = wave * 16 + l15;
            const bf16_t* ah = h1H + ((size_t)t * 64 + brow) * 1024;
            const bf16_t* al = h1L + ((size_t)t * 64 + brow) * 1024;
            #pragma unroll 8
            for (int kk = 0; kk < 32; ++kk) {
                bf16x8 avh = *(const bf16x8*)(ah + kk * 32 + l4 * 8);
                bf16x8 avl = *(const bf16x8*)(al + kk * 32 + l4 * 8);
                int boff = (kk * 64 + l4 * 16) ^ ((l15 & 7) << 4);
                bf16x8 bvh = *(const bf16x8*)(sm + W2H_OFF + l15 * 2048 + boff);
                bf16x8 bvl = *(const bf16x8*)(sm + W2L_OFF + l15 * 2048 + boff);
                acc1 = __builtin_amdgcn_mfma_f32_16x16x32_bf16(avh, bvh, acc1, 0, 0, 0);
                acc1 = __builtin_amdgcn_mfma_f32_16x16x32_bf16(avl, bvh, acc1, 0, 0, 0);
                acc1 = __builtin_amdgcn_mfma_f32_16x16x32_bf16(avh, bvl, acc1, 0, 0, 0);
            }
            if (l15 >= 12) {
                int jq = blk4 + l15 - 12;
                #pragma unroll
                for (int r2 = 0; r2 < 4; ++r2)
                    astore_f32(&qgv[((size_t)t * 64 + (wave * 16 + l4 * 4 + r2)) * 1024 + jq],
                               acc1[r2] + bqv);
            }
        }
        gbar(flags, done, ++epoch, blk, tid);

        // ===== P2 (merged): 64 scores from register cacheK + softmax + PV =====
        {
            const float* qrow = qgv + ((size_t)t * 64 + ab) * 1024;   // q + bq
            float qreg[16];
            #pragma unroll
            for (int i = 0; i < 16; ++i) qreg[i] = qrow[lane + 64 * i];
            #pragma unroll
            for (int sl = 0; sl < 4; ++sl) {
                float sum = 0.f;
                #pragma unroll
                for (int i = 0; i < 16; ++i)
                    sum += tanh_(qreg[i] + ckreg[sl][i]) * vreg[i];
                #pragma unroll
                for (int off = 32; off; off >>= 1) sum += __shfl_down(sum, off, 64);
                if (lane == 0) redp[wave * 4 + sl] = sum;
            }
            asm volatile("s_waitcnt vmcnt(0)" ::: "memory");
            __syncthreads();
            float v = (cmask[ab * 64 + lane] != 0) ? -3.4e38f : redp[lane];
            float mx = v;
            #pragma unroll
            for (int off = 32; off; off >>= 1) mx = fmaxf(mx, __shfl_xor(mx, off, 64));
            float e = __expf(v - mx);
            float sden = e;
            #pragma unroll
            for (int off = 32; off; off >>= 1) sden += __shfl_xor(sden, off, 64);
            float prv = e / sden;

            float sum = 0.f;
            #pragma unroll
            for (int q = 0; q < 16; ++q) {
                float p0 = __shfl(prv, sbase + 2 * q, 64);
                float p1 = __shfl(prv, sbase + 2 * q + 1, 64);
                sum += p0 * __uint_as_float(cr[q] << 16);
                sum += p1 * __uint_as_float(cr[q] & 0xffff0000u);
            }
            sum += __shfl_xor(sum, 1, 64);
            if ((tid & 1) == 0)
                astore_f32(attnseq + ((size_t)ab * T_ + t) * 2048 + cmy, sum);
        }
        gbar(flags, done, ++epoch, blk, tid);

        // ===== P3: gi2 = attn @ W_ih2^T (A split, W hi) + GRU2 =====
        if (wave < 4) {
            f32x4 acc3 = {0.f, 0.f, 0.f, 0.f};
            const int brow = wave * 16 + l15;
            const float* aptr = attnseq + ((size_t)brow * T_ + t) * 2048;
            #pragma unroll 8
            for (int kk = 0; kk < 64; ++kk) {
                bf16x8 avh, avl;
                split8(aptr + kk * 32 + l4 * 8, avh, avl);
                bf16x8 bvh = *(const bf16x8*)(sm + W3H_OFF + l15 * 4096 +
                                              ((kk * 64 + l4 * 16) ^ ((l15 & 7) << 4)));
                acc3 = __builtin_amdgcn_mfma_f32_16x16x32_bf16(avh, bvh, acc3, 0, 0, 0);
                acc3 = __builtin_amdgcn_mfma_f32_16x16x32_bf16(avl, bvh, acc3, 0, 0, 0);
            }
            #pragma unroll
            for (int r2 = 0; r2 < 4; ++r2) {
                float ir  = acc3[r2];
                float iz  = __shfl(acc3[r2], (lane & 48) | (l15 + 4), 64);
                float in2 = __shfl(acc3[r2], (lane & 48) | (l15 + 8), 64);
                float hr  = acc1[r2];
                float hz  = __shfl(acc1[r2], (lane & 48) | (l15 + 4), 64);
                float hn  = __shfl(acc1[r2], (lane & 48) | (l15 + 8), 64);
                int b = wave * 16 + l4 * 4 + r2;
                if (l15 < 4) {
                    float rr = sigm_(ir + bi2r + hr + bh2r);
                    float zz = sigm_(iz + bi2z + hz + bh2z);
                    float nn = tanh_(in2 + bi2n + rr * (hn + bh2n));
                    float h2 = (1.f - zz) * nn + zz * h1r_[r2];
                    hf[b * 1024 + j] = h2;
                    astore_f32(&outseq[((size_t)b * T_ + t) * 1024 + j], h2);
                    if (t == T_ - 1) hfinal[b * 1024 + j] = h2;
                }
            }
        }
        gbar(flags, done, ++epoch, blk, tid);
    }
}

// ===================== final logits =====================
__global__ __launch_bounds__(256)
void final_kernel(const float* __restrict__ Lacc,
                  const float* __restrict__ bi, const float* __restrict__ bh,
                  const float* __restrict__ bc, float* __restrict__ out)
{
    int i = blockIdx.x * 256 + threadIdx.x;
    int e = i & 511;
    out[i] = tanh_(Lacc[i] + bi[e] + bh[e] + bc[e]);
}

// ===================== host =====================
extern "C" void kernel_launch(void* const* d_in, const int* in_sizes, int n_in,
                              void* d_out, int out_size, void* d_ws, size_t ws_size,
                              hipStream_t stream)
{
    const int*   y       = (const int*)  d_in[0];
    const float* context = (const float*)d_in[1];
    const int*   cmask   = (const int*)  d_in[2];
    const float* hidden  = (const float*)d_in[3];
    const float* emb     = (const float*)d_in[4];
    const float* W_ih1   = (const float*)d_in[5];
    const float* W_hh1   = (const float*)d_in[6];
    const float* b_ih1   = (const float*)d_in[7];
    const float* b_hh1   = (const float*)d_in[8];
    const float* Wq      = (const float*)d_in[9];
    const float* bq      = (const float*)d_in[10];
    const float* Wk      = (const float*)d_in[11];
    const float* v_attn  = (const float*)d_in[12];
    const float* W_ih2   = (const float*)d_in[13];
    const float* W_hh2   = (const float*)d_in[14];
    const float* b_ih2   = (const float*)d_in[15];
    const float* b_hh2   = (const float*)d_in[16];
    const float* Wi      = (const float*)d_in[17];
    const float* bi      = (const float*)d_in[18];
    const float* Wh      = (const float*)d_in[19];
    const float* bh      = (const float*)d_in[20];
    const float* Wc      = (const float*)d_in[21];
    const float* bc      = (const float*)d_in[22];

    char* ws = (char*)d_ws;
    size_t o = 0;
    auto alloc = [&](size_t bytes) { char* p = ws + o; o += (bytes + 255) & ~(size_t)255; return p; };
    unsigned* flags = (unsigned*)alloc(NBLK * FLSTR * 4);
    unsigned* done  = (unsigned*)alloc(8 * FLSTR * 4);
    float*  x       = (float*) alloc((size_t)2048 * 512 * 4);
    float*  WkT     = (float*) alloc((size_t)1024 * 2048 * 4);
    float*  WqT     = (float*) alloc((size_t)1024 * 1024 * 4);
    bf16_t* ctxb    = (bf16_t*)alloc((size_t)4096 * 2048 * 2);
    float*  xg2     = (float*) alloc((size_t)2048 * 3072 * 4);      // permuted Xg
    float*  Lacc    = (float*) alloc((size_t)2048 * 512 * 4);
    float*  cacheK  = (float*) alloc((size_t)4096 * 1024 * 4);
    float*  qgv     = (float*) alloc((size_t)T_ * 64 * 1024 * 4);
    float*  hf      = (float*) alloc((size_t)64 * 1024 * 4);
    bf16_t* h1H     = (bf16_t*)alloc((size_t)T_ * 64 * 1024 * 2);
    bf16_t* h1L     = (bf16_t*)alloc((size_t)T_ * 64 * 1024 * 2);
    float*  attnseq = (float*) alloc((size_t)2048 * 2048 * 4);
    float*  outseq  = (float*) alloc((size_t)2048 * 1024 * 4);
    float*  red     = (float*) alloc((size_t)NBLK * 1024 * 4);      // block-private scratch

    hipMemsetAsync(flags, 0, (NBLK * FLSTR + 8 * FLSTR) * 4, stream);

    embed_kernel<<<(B_*T_*E_/4 + 255)/256, 256, 0, stream>>>(y, emb, x);
    transpose_kernel<<<dim3(1024/32, 2048/32), dim3(32,32), 0, stream>>>(Wk, WkT, 2048, 1024);
    transpose_kernel<<<dim3(1024/32, 1024/32), dim3(32,32), 0, stream>>>(Wq, WqT, 1024, 1024);
    cvt_ctx<<<(4096*2048/8)/256, 256, 0, stream>>>(context, ctxb);

    sgemm<0, 1><<<dim3(G_/128, 16), 256, 0, stream>>>(x, W_ih1, xg2, G_, E_);   // Xg permuted
    sgemm<0, 0><<<dim3(E_/128, 16), 256, 0, stream>>>(x, Wi, Lacc, E_, E_);
    sgemm<0, 0><<<dim3(H_/128, 32), 256, 0, stream>>>(context, WkT, cacheK, H_, C_);

    hipFuncSetAttribute((const void*)scan_kernel, hipFuncAttributeMaxDynamicSharedMemorySize, SMEM_BYTES);
    scan_kernel<<<NBLK, 1024, SMEM_BYTES, stream>>>(
        W_hh1, W_hh2, WqT, W_ih2, xg2,
        b_ih1, b_hh1, b_ih2, b_hh2, bq, v_attn, cmask, hidden, cacheK, ctxb,
        qgv, hf, h1H, h1L, attnseq, outseq,
        (float*)d_out + (size_t)B_ * T_ * E_, red, flags, done);

    sgemm<1, 0><<<dim3(E_/128, 16), 256, 0, stream>>>(outseq, Wh, Lacc, E_, H_);
    sgemm<1, 0><<<dim3(E_/128, 16), 256, 0, stream>>>(attnseq, Wc, Lacc, E_, C_);

    final_kernel<<<(B_*T_*E_)/256, 256, 0, stream>>>(Lacc, bi, bh, bc, (float*)d_out);
}

// Round 13
// 2870.301 us; speedup vs baseline: 1.2462x; 1.2356x over previous
//
#include <hip/hip_runtime.h>
#include <math.h>

#define B_ 64
#define T_ 32
#define S_ 64
#define E_ 512
#define H_ 1024
#define C_ 2048
#define G_ 3072
#define NBLK 256
#define FLSTR 16   // 16 uints = 64B padding per flag slot

typedef __bf16 bf16_t;
typedef bf16_t bf16x8 __attribute__((ext_vector_type(8)));
typedef float f32x4 __attribute__((ext_vector_type(4)));
typedef unsigned long long u64;

__device__ __forceinline__ float sigm_(float x) { return 1.f / (1.f + __expf(-x)); }
__device__ __forceinline__ float tanh_(float x) { return 1.f - 2.f / (__expf(2.f * x) + 1.f); }

// ---- bypass (coherence-point) store helpers; loads stay normal/cached ----
__device__ __forceinline__ unsigned short bits_(bf16_t x)
{
    union { bf16_t b; unsigned short u; } c; c.b = x; return c.u;
}
__device__ __forceinline__ void astore_pair(bf16_t* p, bf16_t lo, bf16_t hi)
{
    unsigned u = (unsigned)bits_(lo) | ((unsigned)bits_(hi) << 16);
    __hip_atomic_store((unsigned*)p, u, __ATOMIC_RELAXED, __HIP_MEMORY_SCOPE_AGENT);
}
__device__ __forceinline__ void astore_f32(float* p, float v)
{
    union { float f; unsigned u; } c; c.f = v;
    __hip_atomic_store((unsigned*)p, c.u, __ATOMIC_RELAXED, __HIP_MEMORY_SCOPE_AGENT);
}

// split 8 consecutive f32 into hi/lo bf16x8
__device__ __forceinline__ void split8(const float* __restrict__ p, bf16x8& h, bf16x8& l)
{
    float4 a = *(const float4*)p;
    float4 b = *(const float4*)(p + 4);
    float v[8] = {a.x, a.y, a.z, a.w, b.x, b.y, b.z, b.w};
    #pragma unroll
    for (int q = 0; q < 8; ++q) {
        h[q] = (bf16_t)v[q];
        l[q] = (bf16_t)(v[q] - (float)h[q]);
    }
}

// ===================== helpers =====================
__global__ __launch_bounds__(256)
void embed_kernel(const int* __restrict__ y, const float* __restrict__ emb,
                  float* __restrict__ x)
{
    int i = blockIdx.x * 256 + threadIdx.x;      // B*T*E/4
    int row = i / (E_ / 4);
    int e4  = i % (E_ / 4);
    const float4* src = (const float4*)(emb + (size_t)y[row] * E_);
    ((float4*)(x + (size_t)row * E_))[e4] = src[e4];
}

__global__ void transpose_kernel(const float* __restrict__ in, float* __restrict__ out,
                                 int R, int Ccols)
{
    __shared__ float t[32][33];
    int r0 = blockIdx.y * 32, c0 = blockIdx.x * 32;
    t[threadIdx.y][threadIdx.x] = in[(size_t)(r0 + threadIdx.y) * Ccols + c0 + threadIdx.x];
    __syncthreads();
    out[(size_t)(c0 + threadIdx.y) * R + r0 + threadIdx.x] = t[threadIdx.x][threadIdx.y];
}

__global__ __launch_bounds__(256)
void cvt_ctx(const float* __restrict__ in, bf16_t* __restrict__ out)
{
    int i = blockIdx.x * 256 + threadIdx.x;
    const float4* s4 = (const float4*)in + 2 * i;
    float4 a = s4[0], b = s4[1];
    bf16x8 o;
    o[0] = (bf16_t)a.x; o[1] = (bf16_t)a.y; o[2] = (bf16_t)a.z; o[3] = (bf16_t)a.w;
    o[4] = (bf16_t)b.x; o[5] = (bf16_t)b.y; o[6] = (bf16_t)b.z; o[7] = (bf16_t)b.w;
    ((bf16x8*)out)[i] = o;
}

// ============ split-precision GEMM: f32 A[M,K] @ f32 Wt[N,K]^T -> f32 =======
// PERM=1: write into xg2 layout [j>>2][t][b][gate*4 + (j&3)]
#define LSTR 80

template<int ACCUM, int PERM>
__global__ __launch_bounds__(256)
void sgemm(const float* __restrict__ A, const float* __restrict__ Wt,
           float* __restrict__ out, int N, int K)
{
    __shared__ char AH[128 * LSTR];
    __shared__ char AL[128 * LSTR];
    __shared__ char WH[128 * LSTR];
    __shared__ char WL[128 * LSTR];
    const int tid = threadIdx.x;
    const int lane = tid & 63, wave = tid >> 6;
    const int m0 = blockIdx.y * 128, n0 = blockIdx.x * 128;
    const int wm = (wave & 1) * 64, wn = (wave >> 1) * 64;
    const int l15 = lane & 15, l4 = lane >> 4;

    f32x4 acc[4][4] = {};

    for (int k0 = 0; k0 < K; k0 += 32) {
        #pragma unroll
        for (int p = 0; p < 2; ++p) {
            int e = tid + p * 256;
            int row = e >> 2, ch = e & 3;
            int off = row * LSTR + ch * 16;
            bf16x8 h, l;
            split8(A + (size_t)(m0 + row) * K + k0 + ch * 8, h, l);
            *(bf16x8*)(AH + off) = h; *(bf16x8*)(AL + off) = l;
            split8(Wt + (size_t)(n0 + row) * K + k0 + ch * 8, h, l);
            *(bf16x8*)(WH + off) = h; *(bf16x8*)(WL + off) = l;
        }
        __syncthreads();
        bf16x8 ah[4], al[4], wh[4], wl[4];
        #pragma unroll
        for (int i = 0; i < 4; ++i) {
            int off = (wm + i * 16 + l15) * LSTR + l4 * 16;
            ah[i] = *(const bf16x8*)(AH + off);
            al[i] = *(const bf16x8*)(AL + off);
        }
        #pragma unroll
        for (int j = 0; j < 4; ++j) {
            int off = (wn + j * 16 + l15) * LSTR + l4 * 16;
            wh[j] = *(const bf16x8*)(WH + off);
            wl[j] = *(const bf16x8*)(WL + off);
        }
        #pragma unroll
        for (int i = 0; i < 4; ++i)
            #pragma unroll
            for (int j = 0; j < 4; ++j) {
                acc[i][j] = __builtin_amdgcn_mfma_f32_16x16x32_bf16(ah[i], wh[j], acc[i][j], 0, 0, 0);
                acc[i][j] = __builtin_amdgcn_mfma_f32_16x16x32_bf16(ah[i], wl[j], acc[i][j], 0, 0, 0);
                acc[i][j] = __builtin_amdgcn_mfma_f32_16x16x32_bf16(al[i], wh[j], acc[i][j], 0, 0, 0);
            }
        __syncthreads();
    }

    #pragma unroll
    for (int i = 0; i < 4; ++i)
        #pragma unroll
        for (int j = 0; j < 4; ++j)
            #pragma unroll
            for (int r = 0; r < 4; ++r) {
                int m = m0 + wm + i * 16 + l4 * 4 + r;
                int n = n0 + wn + j * 16 + l15;
                if (PERM) {
                    int b = m >> 5, t = m & 31;
                    int gate = n >> 10, jj = n & 1023;
                    size_t dst = (((size_t)(jj >> 2) * 32 + t) * 64 + b) * 12
                                 + gate * 4 + (jj & 3);
                    out[dst] = acc[i][j][r];
                } else if (ACCUM) {
                    out[(size_t)m * N + n] += acc[i][j][r];
                } else {
                    out[(size_t)m * N + n] = acc[i][j][r];
                }
            }
}

// ===================== persistent scan kernel =====================
#define W1H_OFF 0         // W_hh1 hi : 12 rows x 2048B
#define W1L_OFF 24576     // W_hh1 lo : 12 rows
#define W3H_OFF 49152     // W_ih2 hi : 12 rows x 4096B
#define W2H_OFF 98304     // [W_hh2 gates; WqT] hi : 16 rows x 2048B
#define W2L_OFF 131072    // lo : 16 rows -> ends 163840
#define SMEM_BYTES 163840

// Fence-free barrier (flags are relaxed agent atomics; no L2 invalidation).
__device__ __forceinline__ void gbar(unsigned* flags, unsigned* done,
                                     unsigned epoch, int blk, int tid)
{
    asm volatile("s_waitcnt vmcnt(0)" ::: "memory");
    __syncthreads();
    if (blk == 0) {
        if (tid > 0 && tid < NBLK) {
            while (__hip_atomic_load(&flags[tid * FLSTR], __ATOMIC_RELAXED,
                                     __HIP_MEMORY_SCOPE_AGENT) < epoch)
                __builtin_amdgcn_s_sleep(4);
        }
        __syncthreads();
        if (tid < 8)
            __hip_atomic_store(&done[tid * FLSTR], epoch, __ATOMIC_RELAXED,
                               __HIP_MEMORY_SCOPE_AGENT);
        __syncthreads();
    } else {
        if (tid == 0) {
            __hip_atomic_store(&flags[blk * FLSTR], epoch, __ATOMIC_RELAXED,
                               __HIP_MEMORY_SCOPE_AGENT);
            while (__hip_atomic_load(&done[(blk & 7) * FLSTR], __ATOMIC_RELAXED,
                                     __HIP_MEMORY_SCOPE_AGENT) < epoch)
                __builtin_amdgcn_s_sleep(4);
        }
        __syncthreads();
    }
}

__global__ __launch_bounds__(1024, 4)
void scan_kernel(
    const float* __restrict__ Whh1, const float* __restrict__ Whh2,
    const float* __restrict__ WqT,  const float* __restrict__ Wih2,
    const float* __restrict__ xg2,
    const float* __restrict__ b_ih1, const float* __restrict__ b_hh1,
    const float* __restrict__ b_ih2, const float* __restrict__ b_hh2,
    const float* __restrict__ bq,    const float* __restrict__ v_attn,
    const int*   __restrict__ cmask,
    const float* __restrict__ hidden,
    const float* __restrict__ cacheK, const bf16_t* __restrict__ ctxb,
    float* __restrict__ qgv, float* __restrict__ hf,
    bf16_t* __restrict__ h1H, bf16_t* __restrict__ h1L,
    float* __restrict__ attnseq, float* __restrict__ outseq,
    float* __restrict__ hfinal,
    float* __restrict__ scgv,
    unsigned* __restrict__ flags, unsigned* __restrict__ done)
{
    extern __shared__ char sm[];
    const int tid = threadIdx.x, blk = blockIdx.x;
    const int lane = tid & 63, wave = tid >> 6;   // 16 waves
    const int l15 = lane & 15, l4 = lane >> 4;
    const int blk4 = blk * 4;
    const int ab  = blk & 63;    // attention batch
    const int aq  = blk >> 6;    // attention quarter (0..3)

    // One-time cache invalidate (stale poisoned lines), then only fresh data.
    if (tid == 0) __builtin_amdgcn_fence(__ATOMIC_ACQUIRE, "agent");
    __syncthreads();

    // ---- stage weight slices into LDS as hi/lo bf16 (swizzled) ----
    for (int e = tid; e < 12 * 128; e += 1024) {           // W_hh1 (K=1024)
        int r = e >> 7, c = e & 127;
        bf16x8 h, l;
        split8(Whh1 + (size_t)((r >> 2) * 1024 + blk4 + (r & 3)) * 1024 + c * 8, h, l);
        int off = r * 2048 + ((c * 16) ^ ((r & 7) << 4));
        *(bf16x8*)(sm + W1H_OFF + off) = h;
        *(bf16x8*)(sm + W1L_OFF + off) = l;
    }
    for (int e = tid; e < 16 * 128; e += 1024) {           // [W_hh2 gates; WqT] (K=1024)
        int r = e >> 7, c = e & 127;
        const float* src = (r < 12)
            ? Whh2 + (size_t)((r >> 2) * 1024 + blk4 + (r & 3)) * 1024 + c * 8
            : WqT + (size_t)(blk4 + r - 12) * 1024 + c * 8;
        bf16x8 h, l;
        split8(src, h, l);
        int off = r * 2048 + ((c * 16) ^ ((r & 7) << 4));
        *(bf16x8*)(sm + W2H_OFF + off) = h;
        *(bf16x8*)(sm + W2L_OFF + off) = l;
    }
    for (int e = tid; e < 12 * 256; e += 1024) {           // W_ih2 hi only (K=2048)
        int r = e >> 8, c = e & 255;
        bf16x8 h, l;
        split8(Wih2 + (size_t)((r >> 2) * 1024 + blk4 + (r & 3)) * 2048 + c * 8, h, l);
        *(bf16x8*)(sm + W3H_OFF + r * 4096 + ((c * 16) ^ ((r & 7) << 4))) = h;
    }

    // hf init (thread-private recurrent f32 state)
    const int j = blk4 + l15;
    if (wave < 4 && l15 < 4) {
        #pragma unroll
        for (int r2 = 0; r2 < 4; ++r2) {
            int b = wave * 16 + l4 * 4 + r2;
            hf[b * 1024 + j] = hidden[b * 1024 + j];
        }
    }

    // ---- attention constants pinned in registers (32 regs total) ----
    float vreg[16];
    #pragma unroll
    for (int i = 0; i < 16; ++i) vreg[i] = v_attn[lane + 64 * i];
    // ctx column cmy = aq*512 + tid/2; this thread covers s = sbase..sbase+31
    const int cmy = aq * 512 + (tid >> 1);
    const int sbase = (tid & 1) * 32;
    unsigned cr[16];
    {
        const bf16_t* cb = ctxb + ((size_t)ab * 64 + sbase) * 2048 + cmy;
        #pragma unroll
        for (int q = 0; q < 16; ++q) {
            unsigned lo = bits_(cb[(size_t)(2 * q) * 2048]);
            unsigned hi = bits_(cb[(size_t)(2 * q + 1) * 2048]);
            cr[q] = lo | (hi << 16);
        }
    }

    // per-thread GRU biases (waves 0-3, l15<4) and bq (waves 0-3, l15>=12)
    float bi1r = 0, bi1z = 0, bi1n = 0, bh1r = 0, bh1z = 0, bh1n = 0;
    float bi2r = 0, bi2z = 0, bi2n = 0, bh2r = 0, bh2z = 0, bh2n = 0;
    float bqv = 0.f;
    if (wave < 4 && l15 < 4) {
        bi1r = b_ih1[j]; bi1z = b_ih1[1024 + j]; bi1n = b_ih1[2048 + j];
        bh1r = b_hh1[j]; bh1z = b_hh1[1024 + j]; bh1n = b_hh1[2048 + j];
        bi2r = b_ih2[j]; bi2z = b_ih2[1024 + j]; bi2n = b_ih2[2048 + j];
        bh2r = b_hh2[j]; bh2z = b_hh2[1024 + j]; bh2n = b_hh2[2048 + j];
    }
    if (wave < 4 && l15 >= 12) bqv = bq[blk4 + l15 - 12];

    unsigned epoch = 0;
    gbar(flags, done, ++epoch, blk, tid);

    float h1r_[4] = {0.f, 0.f, 0.f, 0.f};
    f32x4 acc1 = {0.f, 0.f, 0.f, 0.f};

    for (int t = 0; t < T_; ++t) {
        // ===== P0: gh1 = h @ W_hh1^T (split 3-term) + in-register GRU1 =====
        if (wave < 4) {
            f32x4 acc0 = {0.f, 0.f, 0.f, 0.f};
            const int brow = wave * 16 + l15;
            const float* asrc = (t == 0) ? hidden + (size_t)brow * 1024
                                         : outseq + ((size_t)brow * T_ + t - 1) * 1024;
            #pragma unroll 8
            for (int kk = 0; kk < 32; ++kk) {
                bf16x8 avh, avl;
                split8(asrc + kk * 32 + l4 * 8, avh, avl);
                int boff = (kk * 64 + l4 * 16) ^ ((l15 & 7) << 4);
                bf16x8 bvh = *(const bf16x8*)(sm + W1H_OFF + l15 * 2048 + boff);
                bf16x8 bvl = *(const bf16x8*)(sm + W1L_OFF + l15 * 2048 + boff);
                acc0 = __builtin_amdgcn_mfma_f32_16x16x32_bf16(avh, bvh, acc0, 0, 0, 0);
                acc0 = __builtin_amdgcn_mfma_f32_16x16x32_bf16(avl, bvh, acc0, 0, 0, 0);
                acc0 = __builtin_amdgcn_mfma_f32_16x16x32_bf16(avh, bvl, acc0, 0, 0, 0);
            }
            const float* xg = xg2 + (((size_t)blk * 32 + t) * 64) * 12;
            #pragma unroll
            for (int r2 = 0; r2 < 4; ++r2) {
                float gr = acc0[r2];
                float gz = __shfl(acc0[r2], (lane & 48) | (l15 + 4), 64);
                float gn = __shfl(acc0[r2], (lane & 48) | (l15 + 8), 64);
                float h1v = 0.f;
                int b = wave * 16 + l4 * 4 + r2;
                if (l15 < 4) {
                    float rr = sigm_(xg[b * 12 + l15]     + bi1r + gr + bh1r);
                    float zz = sigm_(xg[b * 12 + 4 + l15] + bi1z + gz + bh1z);
                    float nn = tanh_(xg[b * 12 + 8 + l15] + bi1n + rr * (gn + bh1n));
                    h1v = (1.f - zz) * nn + zz * hf[b * 1024 + j];
                    h1r_[r2] = h1v;
                }
                float h1o = __shfl(h1v, lane + 1, 64);
                if (l15 < 4 && (l15 & 1) == 0) {
                    bf16_t hS = (bf16_t)h1v, hO = (bf16_t)h1o;
                    size_t vo = ((size_t)t * 64 + b) * 1024 + j;
                    astore_pair(h1H + vo, hS, hO);
                    astore_pair(h1L + vo,
                                (bf16_t)(h1v - (float)hS), (bf16_t)(h1o - (float)hO));
                }
            }
        } else {
            // prefetch this phase's h-source (and xg2 slab) into L2
            int pid = tid - 256;                 // 0..767
            float accp = 0.f;
            if (t == 0) {
                const float4* src = (const float4*)hidden;          // 16384 float4
                for (int i = pid; i < 16384; i += 768) {
                    float4 v = src[i];
                    accp += v.x + v.y + v.z + v.w;
                }
            } else {
                for (int i = pid; i < 16384; i += 768) {
                    int row = i >> 8, c4 = i & 255;
                    float4 v = ((const float4*)(outseq + ((size_t)row * T_ + t - 1) * 1024))[c4];
                    accp += v.x + v.y + v.z + v.w;
                }
            }
            if (pid < 192) {                     // xg2: 64*12 f32 = 192 float4
                float4 v = ((const float4*)(xg2 + (((size_t)blk * 32 + t) * 64) * 12))[pid];
                accp += v.x + v.y + v.z + v.w;
            }
            asm volatile("" :: "v"(accp));
        }
        gbar(flags, done, ++epoch, blk, tid);

        // ===== P1: [gh2 | q] = h1 @ [W_hh2 ; WqT]^T (split 3-term) =====
        if (wave < 4) {
            acc1 = (f32x4){0.f, 0.f, 0.f, 0.f};
            const int brow = wave * 16 + l15;
            const bf16_t* ah = h1H + ((size_t)t * 64 + brow) * 1024;
            const bf16_t* al = h1L + ((size_t)t * 64 + brow) * 1024;
            #pragma unroll 8
            for (int kk = 0; kk < 32; ++kk) {
                bf16x8 avh = *(const bf16x8*)(ah + kk * 32 + l4 * 8);
                bf16x8 avl = *(const bf16x8*)(al + kk * 32 + l4 * 8);
                int boff = (kk * 64 + l4 * 16) ^ ((l15 & 7) << 4);
                bf16x8 bvh = *(const bf16x8*)(sm + W2H_OFF + l15 * 2048 + boff);
                bf16x8 bvl = *(const bf16x8*)(sm + W2L_OFF + l15 * 2048 + boff);
                acc1 = __builtin_amdgcn_mfma_f32_16x16x32_bf16(avh, bvh, acc1, 0, 0, 0);
                acc1 = __builtin_amdgcn_mfma_f32_16x16x32_bf16(avl, bvh, acc1, 0, 0, 0);
                acc1 = __builtin_amdgcn_mfma_f32_16x16x32_bf16(avh, bvl, acc1, 0, 0, 0);
            }
            if (l15 >= 12) {
                int jq = blk4 + l15 - 12;
                #pragma unroll
                for (int r2 = 0; r2 < 4; ++r2)
                    astore_f32(&qgv[((size_t)t * 64 + (wave * 16 + l4 * 4 + r2)) * 1024 + jq],
                               acc1[r2] + bqv);
            }
        } else {
            // prefetch h1H/h1L (contiguous 8192 float4 each) into L2
            int pid = tid - 256;
            float accp = 0.f;
            const float4* s1 = (const float4*)(h1H + (size_t)t * 65536);
            const float4* s2 = (const float4*)(h1L + (size_t)t * 65536);
            for (int i = pid; i < 8192; i += 768) {
                float4 a = s1[i], b = s2[i];
                accp += a.x + a.w + b.x + b.w;
            }
            asm volatile("" :: "v"(accp));
        }
        gbar(flags, done, ++epoch, blk, tid);

        // ===== P2a: scores (batch ab, quarter aq; one s per wave) =====
        {
            int s = aq * 16 + wave;
            const float* qrow = qgv + ((size_t)t * 64 + ab) * 1024;   // q + bq
            const float* ck = cacheK + ((size_t)ab * 64 + s) * 1024;  // L2-resident
            float sum = 0.f;
            #pragma unroll
            for (int i = 0; i < 16; ++i)
                sum += tanh_(qrow[lane + 64 * i] + ck[lane + 64 * i]) * vreg[i];
            #pragma unroll
            for (int off = 32; off; off >>= 1) sum += __shfl_down(sum, off, 64);
            if (lane == 0) astore_f32(&scgv[(size_t)t * 4096 + ab * 64 + s], sum);
        }
        gbar(flags, done, ++epoch, blk, tid);

        // ===== P2b: softmax + PV from register ctx (1024 threads, 2/col) =====
        {
            const float* scrow = scgv + (size_t)t * 4096 + ab * 64;
            float v = (cmask[ab * 64 + lane] != 0) ? -3.4e38f : scrow[lane];
            float mx = v;
            #pragma unroll
            for (int off = 32; off; off >>= 1) mx = fmaxf(mx, __shfl_xor(mx, off, 64));
            float e = __expf(v - mx);
            float sden = e;
            #pragma unroll
            for (int off = 32; off; off >>= 1) sden += __shfl_xor(sden, off, 64);
            float prv = e / sden;

            float sum = 0.f;
            #pragma unroll
            for (int q = 0; q < 16; ++q) {
                float p0 = __shfl(prv, sbase + 2 * q, 64);
                float p1 = __shfl(prv, sbase + 2 * q + 1, 64);
                sum += p0 * __uint_as_float(cr[q] << 16);
                sum += p1 * __uint_as_float(cr[q] & 0xffff0000u);
            }
            sum += __shfl_xor(sum, 1, 64);
            if ((tid & 1) == 0)
                astore_f32(attnseq + ((size_t)ab * T_ + t) * 2048 + cmy, sum);
        }
        gbar(flags, done, ++epoch, blk, tid);

        // ===== P3: gi2 = attn @ W_ih2^T (A split, W hi) + GRU2 =====
        if (wave < 4) {
            f32x4 acc3 = {0.f, 0.f, 0.f, 0.f};
            const int brow = wave * 16 + l15;
            const float* aptr = attnseq + ((size_t)brow * T_ + t) * 2048;
            #pragma unroll 8
            for (int kk = 0; kk < 64; ++kk) {
                bf16x8 avh, avl;
                split8(aptr + kk * 32 + l4 * 8, avh, avl);
                bf16x8 bvh = *(const bf16x8*)(sm + W3H_OFF + l15 * 4096 +
                                              ((kk * 64 + l4 * 16) ^ ((l15 & 7) << 4)));
                acc3 = __builtin_amdgcn_mfma_f32_16x16x32_bf16(avh, bvh, acc3, 0, 0, 0);
                acc3 = __builtin_amdgcn_mfma_f32_16x16x32_bf16(avl, bvh, acc3, 0, 0, 0);
            }
            #pragma unroll
            for (int r2 = 0; r2 < 4; ++r2) {
                float ir  = acc3[r2];
                float iz  = __shfl(acc3[r2], (lane & 48) | (l15 + 4), 64);
                float in2 = __shfl(acc3[r2], (lane & 48) | (l15 + 8), 64);
                float hr  = acc1[r2];
                float hz  = __shfl(acc1[r2], (lane & 48) | (l15 + 4), 64);
                float hn  = __shfl(acc1[r2], (lane & 48) | (l15 + 8), 64);
                int b = wave * 16 + l4 * 4 + r2;
                if (l15 < 4) {
                    float rr = sigm_(ir + bi2r + hr + bh2r);
                    float zz = sigm_(iz + bi2z + hz + bh2z);
                    float nn = tanh_(in2 + bi2n + rr * (hn + bh2n));
                    float h2 = (1.f - zz) * nn + zz * h1r_[r2];
                    hf[b * 1024 + j] = h2;
                    astore_f32(&outseq[((size_t)b * T_ + t) * 1024 + j], h2);
                    if (t == T_ - 1) hfinal[b * 1024 + j] = h2;
                }
            }
        } else {
            // prefetch attnseq rows (64 rows x 512 float4) into L2
            int pid = tid - 256;
            float accp = 0.f;
            for (int i = pid; i < 32768; i += 768) {
                int row = i >> 9, c4 = i & 511;
                float4 v = ((const float4*)(attnseq + ((size_t)row * T_ + t) * 2048))[c4];
                accp += v.x + v.y + v.z + v.w;
            }
            asm volatile("" :: "v"(accp));
        }
        gbar(flags, done, ++epoch, blk, tid);
    }
}

// ===================== final logits =====================
__global__ __launch_bounds__(256)
void final_kernel(const float* __restrict__ Lacc,
                  const float* __restrict__ bi, const float* __restrict__ bh,
                  const float* __restrict__ bc, float* __restrict__ out)
{
    int i = blockIdx.x * 256 + threadIdx.x;
    int e = i & 511;
    out[i] = tanh_(Lacc[i] + bi[e] + bh[e] + bc[e]);
}

// ===================== host =====================
extern "C" void kernel_launch(void* const* d_in, const int* in_sizes, int n_in,
                              void* d_out, int out_size, void* d_ws, size_t ws_size,
                              hipStream_t stream)
{
    const int*   y       = (const int*)  d_in[0];
    const float* context = (const float*)d_in[1];
    const int*   cmask   = (const int*)  d_in[2];
    const float* hidden  = (const float*)d_in[3];
    const float* emb     = (const float*)d_in[4];
    const float* W_ih1   = (const float*)d_in[5];
    const float* W_hh1   = (const float*)d_in[6];
    const float* b_ih1   = (const float*)d_in[7];
    const float* b_hh1   = (const float*)d_in[8];
    const float* Wq      = (const float*)d_in[9];
    const float* bq      = (const float*)d_in[10];
    const float* Wk      = (const float*)d_in[11];
    const float* v_attn  = (const float*)d_in[12];
    const float* W_ih2   = (const float*)d_in[13];
    const float* W_hh2   = (const float*)d_in[14];
    const float* b_ih2   = (const float*)d_in[15];
    const float* b_hh2   = (const float*)d_in[16];
    const float* Wi      = (const float*)d_in[17];
    const float* bi      = (const float*)d_in[18];
    const float* Wh      = (const float*)d_in[19];
    const float* bh      = (const float*)d_in[20];
    const float* Wc      = (const float*)d_in[21];
    const float* bc      = (const float*)d_in[22];

    char* ws = (char*)d_ws;
    size_t o = 0;
    auto alloc = [&](size_t bytes) { char* p = ws + o; o += (bytes + 255) & ~(size_t)255; return p; };
    unsigned* flags = (unsigned*)alloc(NBLK * FLSTR * 4);
    unsigned* done  = (unsigned*)alloc(8 * FLSTR * 4);
    float*  x       = (float*) alloc((size_t)2048 * 512 * 4);
    float*  WkT     = (float*) alloc((size_t)1024 * 2048 * 4);
    float*  WqT     = (float*) alloc((size_t)1024 * 1024 * 4);
    bf16_t* ctxb    = (bf16_t*)alloc((size_t)4096 * 2048 * 2);
    float*  xg2     = (float*) alloc((size_t)2048 * 3072 * 4);      // permuted Xg
    float*  Lacc    = (float*) alloc((size_t)2048 * 512 * 4);
    float*  cacheK  = (float*) alloc((size_t)4096 * 1024 * 4);
    float*  qgv     = (float*) alloc((size_t)T_ * 64 * 1024 * 4);
    float*  hf      = (float*) alloc((size_t)64 * 1024 * 4);
    bf16_t* h1H     = (bf16_t*)alloc((size_t)T_ * 64 * 1024 * 2);
    bf16_t* h1L     = (bf16_t*)alloc((size_t)T_ * 64 * 1024 * 2);
    float*  attnseq = (float*) alloc((size_t)2048 * 2048 * 4);
    float*  outseq  = (float*) alloc((size_t)2048 * 1024 * 4);
    float*  scgv    = (float*) alloc((size_t)T_ * 64 * 64 * 4);

    hipMemsetAsync(flags, 0, (NBLK * FLSTR + 8 * FLSTR) * 4, stream);

    embed_kernel<<<(B_*T_*E_/4 + 255)/256, 256, 0, stream>>>(y, emb, x);
    transpose_kernel<<<dim3(1024/32, 2048/32), dim3(32,32), 0, stream>>>(Wk, WkT, 2048, 1024);
    transpose_kernel<<<dim3(1024/32, 1024/32), dim3(32,32), 0, stream>>>(Wq, WqT, 1024, 1024);
    cvt_ctx<<<(4096*2048/8)/256, 256, 0, stream>>>(context, ctxb);

    sgemm<0, 1><<<dim3(G_/128, 16), 256, 0, stream>>>(x, W_ih1, xg2, G_, E_);   // Xg permuted
    sgemm<0, 0><<<dim3(E_/128, 16), 256, 0, stream>>>(x, Wi, Lacc, E_, E_);
    sgemm<0, 0><<<dim3(H_/128, 32), 256, 0, stream>>>(context, WkT, cacheK, H_, C_);

    hipFuncSetAttribute((const void*)scan_kernel, hipFuncAttributeMaxDynamicSharedMemorySize, SMEM_BYTES);
    scan_kernel<<<NBLK, 1024, SMEM_BYTES, stream>>>(
        W_hh1, W_hh2, WqT, W_ih2, xg2,
        b_ih1, b_hh1, b_ih2, b_hh2, bq, v_attn, cmask, hidden, cacheK, ctxb,
        qgv, hf, h1H, h1L, attnseq, outseq,
        (float*)d_out + (size_t)B_ * T_ * E_, scgv, flags, done);

    sgemm<1, 0><<<dim3(E_/128, 16), 256, 0, stream>>>(outseq, Wh, Lacc, E_, H_);
    sgemm<1, 0><<<dim3(E_/128, 16), 256, 0, stream>>>(attnseq, Wc, Lacc, E_, C_);

    final_kernel<<<(B_*T_*E_)/256, 256, 0, stream>>>(Lacc, bi, bh, bc, (float*)d_out);
}